// Round 3
// baseline (192.228 us; speedup 1.0000x reference)
//
#include <hip/hip_runtime.h>
#include <hip/hip_fp16.h>

#define NN   50000
#define EE   800000
#define KDIN 128
#define NH   4
#define ND   16
#define NEG_SLOPE 0.2f

__device__ __forceinline__ float lrelu(float x) {
    return x > 0.f ? x : NEG_SLOPE * x;
}
__device__ __forceinline__ float h2f(unsigned short u) {
    return __half2float(__ushort_as_half(u));
}

// ---- K1: feat = h @ W  (N x 128 @ 128 x 64) -> fp16 feat + f32 el/er ----
// block = 256 threads = 4 waves; each wave handles 4 rows; each lane owns a
// float4 of columns (c4 = lane&15 -> cols 4*c4..4*c4+3, all within one head).
__global__ __launch_bounds__(256) void k_proj(
    const float* __restrict__ h, const float* __restrict__ W,
    const float* __restrict__ attn_l, const float* __restrict__ attn_r,
    unsigned short* __restrict__ feat_h, float* __restrict__ el, float* __restrict__ er)
{
    __shared__ float4 Wl[KDIN * 16];   // [k][c4] : 32 KB, whole W
    __shared__ float  hrow[16 * 132];  // 16 rows padded to 132 (bank-conflict-free)

    const int tid = threadIdx.x;
    const float4* W4 = (const float4*)W;
    #pragma unroll
    for (int i = 0; i < 8; ++i) Wl[tid + 256 * i] = W4[tid + 256 * i];

    const int wave = tid >> 6;
    const int lane = tid & 63;
    const int r16  = lane >> 4;   // which of the wave's 4 rows
    const int c4   = lane & 15;   // float4 column index
    const int row_base = blockIdx.x * 16 + wave * 4;

    {
        const float4* h4 = (const float4*)h;
        float4 v0 = h4[(size_t)row_base * 32 + lane];
        float4 v1 = h4[(size_t)row_base * 32 + lane + 64];
        const int i1 = lane + 64;
        *(float4*)&hrow[(wave * 4 + (lane >> 5)) * 132 + (lane & 31) * 4] = v0;
        *(float4*)&hrow[(wave * 4 + (i1  >> 5)) * 132 + (i1  & 31) * 4] = v1;
    }
    __syncthreads();

    const float* myrow = &hrow[(wave * 4 + r16) * 132];
    float4 acc = make_float4(0.f, 0.f, 0.f, 0.f);
    #pragma unroll 8
    for (int k = 0; k < KDIN; ++k) {
        float  hv = myrow[k];
        float4 w  = Wl[k * 16 + c4];
        acc.x = fmaf(hv, w.x, acc.x);
        acc.y = fmaf(hv, w.y, acc.y);
        acc.z = fmaf(hv, w.z, acc.z);
        acc.w = fmaf(hv, w.w, acc.w);
    }
    const int row = row_base + r16;

    // fp16 feat store: one 8B ushort4 per thread, fully coalesced
    ushort4 hv4;
    hv4.x = __half_as_ushort(__float2half_rn(acc.x));
    hv4.y = __half_as_ushort(__float2half_rn(acc.y));
    hv4.z = __half_as_ushort(__float2half_rn(acc.z));
    hv4.w = __half_as_ushort(__float2half_rn(acc.w));
    ((ushort4*)feat_h)[(size_t)row * 16 + c4] = hv4;

    // el/er from full-precision acc
    const float4 al = ((const float4*)attn_l)[c4];
    const float4 ar = ((const float4*)attn_r)[c4];
    float pl = acc.x*al.x + acc.y*al.y + acc.z*al.z + acc.w*al.w;
    float pr = acc.x*ar.x + acc.y*ar.y + acc.z*ar.z + acc.w*ar.w;
    pl += __shfl_xor(pl, 1); pl += __shfl_xor(pl, 2);
    pr += __shfl_xor(pr, 1); pr += __shfl_xor(pr, 2);
    if ((c4 & 3) == 0) {
        const int head = c4 >> 2;
        el[row * NH + head] = pl;
        er[row * NH + head] = pr;
    }
}

// ---- K2: denom[t,h] = sum_{e: dst=t} exp(lrelu(el[s]+er[t])) ----
// One thread per (edge, head); no max-subtraction (logits O(1) by construction,
// softmax shift-invariant; validated R2 absmax 9.8e-4). No ebuf — k_agg
// recomputes ex from the L2-resident el/er tables.
__global__ __launch_bounds__(256) void k_edge(
    const int* __restrict__ src, const int* __restrict__ dst,
    const float* __restrict__ el, const float* __restrict__ er,
    float* __restrict__ denom)
{
    const int i = blockIdx.x * 256 + threadIdx.x;   // E*NH total
    const int edge = i >> 2;
    const int hd   = i & 3;
    const int s = src[edge], t = dst[edge];
    const float e = lrelu(el[s * NH + hd] + er[t * NH + hd]);
    atomicAdd(&denom[t * NH + hd], __expf(e));
}

// ---- K3: out[t,d] += 0.25 * sum_h exp(e)/denom * feat_h[s,h,d] ----
// one thread per (edge, d); recomputes the 4 head weights from el/er/denom
// (all L2-hit); fp16 feat gather = 128B/edge logical; head-sum in registers
// -> 1 atomic per (edge,d), 16 adjacent lanes merge into one 64B line.
__global__ __launch_bounds__(256) void k_agg(
    const int* __restrict__ src, const int* __restrict__ dst,
    const float* __restrict__ el, const float* __restrict__ er,
    const float* __restrict__ denom,
    const unsigned short* __restrict__ feat_h, float* __restrict__ out)
{
    const int idx  = blockIdx.x * 256 + threadIdx.x;  // E*16 total
    const int edge = idx >> 4;
    const int d    = idx & 15;
    const int s = src[edge], t = dst[edge];
    const float4 l  = ((const float4*)el)[s];
    const float4 r  = ((const float4*)er)[t];
    const float4 dn = ((const float4*)denom)[t];
    const float w0 = __expf(lrelu(l.x + r.x)) * __builtin_amdgcn_rcpf(dn.x);
    const float w1 = __expf(lrelu(l.y + r.y)) * __builtin_amdgcn_rcpf(dn.y);
    const float w2 = __expf(lrelu(l.z + r.z)) * __builtin_amdgcn_rcpf(dn.z);
    const float w3 = __expf(lrelu(l.w + r.w)) * __builtin_amdgcn_rcpf(dn.w);
    const unsigned short* f = feat_h + (size_t)s * (NH * ND) + d;
    float acc = w0 * h2f(f[0])
              + w1 * h2f(f[ND])
              + w2 * h2f(f[2 * ND])
              + w3 * h2f(f[3 * ND]);
    atomicAdd(&out[t * ND + d], acc * 0.25f);
}

extern "C" void kernel_launch(void* const* d_in, const int* in_sizes, int n_in,
                              void* d_out, int out_size, void* d_ws, size_t ws_size,
                              hipStream_t stream)
{
    const float* h  = (const float*)d_in[0];
    const float* W  = (const float*)d_in[1];
    const float* al = (const float*)d_in[2];
    const float* ar = (const float*)d_in[3];
    const int* src  = (const int*)d_in[4];
    const int* dst  = (const int*)d_in[5];
    float* out = (float*)d_out;

    // workspace layout (all 16B aligned)
    unsigned short* feat_h = (unsigned short*)d_ws;          // N*64 fp16 (6.4 MB)
    float* el    = (float*)(feat_h + (size_t)NN * 64);       // N*4 f32
    float* er    = el + (size_t)NN * NH;                     // N*4 f32
    float* denom = er + (size_t)NN * NH;                     // N*4 f32

    hipMemsetAsync(denom, 0, (size_t)NN * NH * sizeof(float), stream);
    hipMemsetAsync(out,   0, (size_t)NN * ND * sizeof(float), stream);

    k_proj<<<NN / 16,       256, 0, stream>>>(h, W, al, ar, feat_h, el, er);
    k_edge<<<EE * NH / 256, 256, 0, stream>>>(src, dst, el, er, denom);
    k_agg <<<EE * ND / 256, 256, 0, stream>>>(src, dst, el, er, denom, feat_h, out);
}